// Round 10
// baseline (535.874 us; speedup 1.0000x reference)
//
#include <hip/hip_runtime.h>
#include <math.h>

#define DINL __device__ __forceinline__

typedef __attribute__((ext_vector_type(8))) short short8;   // 8 bf16
typedef __attribute__((ext_vector_type(4))) short short4x;  // 4 bf16
typedef __attribute__((ext_vector_type(4))) float f32x4;    // MFMA acc
typedef unsigned short ushortx;
typedef unsigned int uintx;

// ---------------- geometry ----------------
// image: [1536][48][72]
// conv1: -> [32][23][35]  (805 sp), bf16 hi/lo planes in LDS (swizzled)
// conv2: -> [64][11][17]  (187 sp), MFMA, result kept in LDS as bf16 hi/lo
// conv3: -> [32][5][8]    (40 sp),  MFMA (fused, same block) -> gx[1283]
// LTC: UNITS=48, ODE_UNFOLDS=6, S=48, B=32

static constexpr int O_X    = 0;                         // [1536][1283]
static constexpr int O_WNUM = O_X + 1536 * 1283;         // [1536][48]
static constexpr int O_WDEN = O_WNUM + 1536 * 48;
static constexpr int O_SP4  = O_WDEN + 1536 * 48;        // float4 [48j][1283i]
static constexpr int O_W1H  = O_SP4 + 4 * 48 * 1283;     // ushort [9tap][64oc][32c]
static constexpr int O_W1L  = O_W1H + 9216;
static constexpr int O_W3H  = O_W1L + 9216;              // ushort [9tap][32oc][64c]
static constexpr int O_W3L  = O_W3H + 9216;
static constexpr int O_R4   = O_W3L + 9216;              // float4 [48i][48j]

DINL float sigmoid_f(float z) {
  return __builtin_amdgcn_rcpf(1.f + __expf(-z));
}

DINL ushortx bf16_rne(float x) {
  uintx u = __float_as_uint(x);
  return (ushortx)((u + 0x7FFFu + ((u >> 16) & 1u)) >> 16);
}

// LDS spatial-stride bank-conflict swizzle (involution; xor bits derived from
// higher bits only). ushort-unit index.
DINL int swz(int sp, int idx) { return idx ^ (((sp >> 1) & 7) << 3); }

// -------- pre-pass: sensory pack + rec pack + w1/w3 bf16 hi/lo splits ------
__global__ __launch_bounds__(256) void k_pre(
    const float* __restrict__ ssig, const float* __restrict__ smu,
    const float* __restrict__ sw, const float* __restrict__ serev,
    const int* __restrict__ smask,
    const float* __restrict__ w_syn, const float* __restrict__ erev,
    const int* __restrict__ syn_mask,
    const float* __restrict__ gmu, const float* __restrict__ gsig,
    const float* __restrict__ w1, const float* __restrict__ w2,
    float4* __restrict__ o_p4, float4* __restrict__ o_r4,
    ushortx* __restrict__ w1h, ushortx* __restrict__ w1l,
    ushortx* __restrict__ w3h, ushortx* __restrict__ w3l) {
  const int bid = blockIdx.x, t = threadIdx.x;
  if (bid < 241) {
    int idx = bid * 256 + t;
    if (idx < 61584) {
      int i = idx / 48, j = idx - i * 48;
      float m = (float)smask[idx];
      float w = sw[idx] * m;
      o_p4[j * 1283 + i] = make_float4(ssig[idx], smu[idx], w, w * serev[idx]);
    }
  } else if (bid < 250) {
    int idx = (bid - 241) * 256 + t;
    if (idx < 2304) {
      float wm = w_syn[idx] * (float)syn_mask[idx];
      o_r4[idx] = make_float4(gmu[idx], gsig[idx], wm, wm * erev[idx]);
    }
  } else {
    int idx = (bid - 250) * 256 + t;
    if (idx < 18432) {          // w1 [64oc][32c][9k] -> [k][oc][c] hi/lo
      int oc = idx / 288;
      int rem = idx - oc * 288;
      int c = rem / 9, k = rem - c * 9;
      float v = w1[idx];
      ushortx h = bf16_rne(v);
      float hv = __uint_as_float(((uintx)h) << 16);
      ushortx l = bf16_rne(v - hv);
      int dst = (k * 64 + oc) * 32 + c;
      w1h[dst] = h; w1l[dst] = l;
    } else if (idx < 36864) {   // w2 [32oc][64c][9k] -> [k][oc][c] hi/lo
      int i2 = idx - 18432;
      int oc = i2 / 576;
      int rem = i2 - oc * 576;
      int c = rem / 9, k = rem - c * 9;
      float v = w2[i2];
      ushortx h = bf16_rne(v);
      float hv = __uint_as_float(((uintx)h) << 16);
      ushortx l = bf16_rne(v - hv);
      int dst = (k * 32 + oc) * 64 + c;
      w3h[dst] = h; w3l[dst] = l;
    }
  }
}

// -------- fused conv1 + conv2(MFMA) + conv3(MFMA), one block per image -----
// LDS 121088 B: c1 hi/lo [23][36][32c] bf16 swizzled (reused as o2 planes
// [187][64c] for conv3) + img fp32 + w0/b0. A-frags (weights) streamed
// directly from global (L2-hot, identical across blocks) — no staging
// barriers. 8 waves: conv2 wave=(mt0=2*(w&1), nt0=3*(w>>1)); conv3 waves
// 0..5 = (mt=w&1, nt=w>>1).
__global__ __launch_bounds__(512) void k_cnn(const float* __restrict__ gimg,
        const float* __restrict__ w0, const float* __restrict__ b0,
        const ushortx* __restrict__ w1h, const ushortx* __restrict__ w1l,
        const float* __restrict__ b1,
        const ushortx* __restrict__ w3h, const ushortx* __restrict__ w3l,
        const float* __restrict__ b2,
        const float* __restrict__ grel, float* __restrict__ gx) {
  extern __shared__ __align__(16) char dyn[];
  ushortx* c1h = (ushortx*)dyn;                 // 26496 us (o2h aliases base)
  ushortx* c1l = c1h + 26496;                   // 26496 us (o2l aliases base)
  float* simg = (float*)(c1l + 26496);          // 3456 fl
  float* sw0 = simg + 3456;                     // 288
  float* sb0 = sw0 + 288;                       // 32
  ushortx* o2h = c1h;                           // [187][64] bf16 hi (swizzled)
  ushortx* o2l = c1l;

  const int n = blockIdx.x, t = threadIdx.x;

  const float* gi = gimg + n * 3456;
  for (int k = t; k < 3456; k += 512) simg[k] = gi[k];
  if (t < 288) sw0[t] = w0[t];
  if (t >= 480) sb0[t - 480] = b0[t - 480];

  const int lane = t & 63, wid = t >> 6;
  const int r15 = lane & 15, kg = lane >> 4;
  const int mt0 = (wid & 1) * 2;
  const int nt0 = (wid >> 1) * 3;
  int b36[3], spv[3];
#pragma unroll
  for (int ni = 0; ni < 3; ++ni) {
    int sp = (nt0 + ni) * 16 + r15;
    spv[ni] = sp;
    int spc = sp > 186 ? 186 : sp;
    int oh = spc / 17, ow = spc - oh * 17;
    b36[ni] = (2 * oh) * 36 + 2 * ow;           // spatial idx in c1 planes
  }
  float4 bb[2];
  bb[0] = *(const float4*)(b1 + mt0 * 16 + kg * 4);
  bb[1] = *(const float4*)(b1 + (mt0 + 1) * 16 + kg * 4);
  f32x4 acc[2][3];
#pragma unroll
  for (int mi = 0; mi < 2; ++mi)
#pragma unroll
    for (int ni = 0; ni < 3; ++ni) acc[mi][ni] = (f32x4)(0.f);

  __syncthreads();

  // conv1 -> swizzled hi/lo bf16 planes [sp36][32c]
  for (int idx = t; idx < 25760; idx += 512) {
    int c = idx & 31, sp = idx >> 5;            // sp < 805
    int oh = sp / 35, ow = sp - oh * 35;
    const float* ip = simg + (2 * oh) * 72 + 2 * ow;
    const float* wp = sw0 + c * 9;
    float a = sb0[c];
#pragma unroll
    for (int kh = 0; kh < 3; ++kh)
      a += ip[kh * 72 + 0] * wp[kh * 3 + 0] + ip[kh * 72 + 1] * wp[kh * 3 + 1]
         + ip[kh * 72 + 2] * wp[kh * 3 + 2];
    a = fmaxf(a, 0.f);
    ushortx h = bf16_rne(a);
    float hv = __uint_as_float(((uintx)h) << 16);
    ushortx l = bf16_rne(a - hv);
    int sp36 = oh * 36 + ow;
    int pos = swz(sp36, sp36 * 32 + c);
    c1h[pos] = h;
    c1l[pos] = l;
  }
  __syncthreads();

  // conv2: 9 taps, A from global (L2), B from swizzled c1 planes
  for (int tap = 0; tap < 9; ++tap) {
    const int kh = tap / 3, kw = tap - kh * 3;
    short8 ah[2], al[2];
#pragma unroll
    for (int mi = 0; mi < 2; ++mi) {
      int aoff = (tap * 64 + (mt0 + mi) * 16 + r15) * 32 + kg * 8;
      ah[mi] = *(const short8*)(w1h + aoff);
      al[mi] = *(const short8*)(w1l + aoff);
    }
#pragma unroll
    for (int ni = 0; ni < 3; ++ni) {
      int sp36 = b36[ni] + kh * 36 + kw;
      int bidx = swz(sp36, sp36 * 32 + kg * 8);
      short8 bh = *(const short8*)(c1h + bidx);
      short8 bl = *(const short8*)(c1l + bidx);
#pragma unroll
      for (int mi = 0; mi < 2; ++mi) {
        acc[mi][ni] = __builtin_amdgcn_mfma_f32_16x16x32_bf16(ah[mi], bh, acc[mi][ni], 0, 0, 0);
        acc[mi][ni] = __builtin_amdgcn_mfma_f32_16x16x32_bf16(al[mi], bh, acc[mi][ni], 0, 0, 0);
        acc[mi][ni] = __builtin_amdgcn_mfma_f32_16x16x32_bf16(ah[mi], bl, acc[mi][ni], 0, 0, 0);
      }
    }
  }

  __syncthreads();   // all conv2 c1-plane reads done; planes become o2

  // bias+relu, bf16 hi/lo split, write o2 planes (swizzled [sp][64c])
#pragma unroll
  for (int mi = 0; mi < 2; ++mi)
#pragma unroll
    for (int ni = 0; ni < 3; ++ni) {
      if (spv[ni] < 187) {
        short4x h4, l4;
#pragma unroll
        for (int r = 0; r < 4; ++r) {
          float v = fmaxf(acc[mi][ni][r] + ((const float*)&bb[mi])[r], 0.f);
          ushortx h = bf16_rne(v);
          float hv = __uint_as_float(((uintx)h) << 16);
          h4[r] = (short)h;
          l4[r] = (short)bf16_rne(v - hv);
        }
        int base = swz(spv[ni], spv[ni] * 64 + (mt0 + mi) * 16 + kg * 4);
        *(short4x*)(o2h + base) = h4;
        *(short4x*)(o2l + base) = l4;
      }
    }
  __syncthreads();

  // conv3 (waves 0..5): M=32oc (mt), N=40sp pad48 (nt), K=9tap x 64c
  if (wid < 6) {
    const int mt = wid & 1, nt = wid >> 1;
    int sp_out = nt * 16 + r15;
    int spc3 = sp_out > 39 ? 39 : sp_out;
    int oh3 = spc3 >> 3, ow3 = spc3 & 7;
    f32x4 a3 = (f32x4)(0.f);
    for (int tap = 0; tap < 9; ++tap) {
      const int kh = tap / 3, kw = tap - kh * 3;
      int sp_in = (2 * oh3 + kh) * 17 + (2 * ow3 + kw);
#pragma unroll
      for (int ks = 0; ks < 2; ++ks) {
        int aoff = (tap * 32 + mt * 16 + r15) * 64 + ks * 32 + kg * 8;
        short8 ah3 = *(const short8*)(w3h + aoff);
        short8 al3 = *(const short8*)(w3l + aoff);
        int bidx = swz(sp_in, sp_in * 64 + ks * 32 + kg * 8);
        short8 bh = *(const short8*)(o2h + bidx);
        short8 bl = *(const short8*)(o2l + bidx);
        a3 = __builtin_amdgcn_mfma_f32_16x16x32_bf16(ah3, bh, a3, 0, 0, 0);
        a3 = __builtin_amdgcn_mfma_f32_16x16x32_bf16(al3, bh, a3, 0, 0, 0);
        a3 = __builtin_amdgcn_mfma_f32_16x16x32_bf16(ah3, bl, a3, 0, 0, 0);
      }
    }
    if (sp_out < 40) {
      float* xo = gx + n * 1283;
#pragma unroll
      for (int r = 0; r < 4; ++r) {
        int oc = mt * 16 + kg * 4 + r;
        xo[oc * 40 + sp_out] = fmaxf(a3[r] + b2[oc], 0.f);
      }
    }
  }
  if (t < 3) gx[n * 1283 + 1280 + t] = grel[n * 3 + t];
}

// -------- sensory synapse sums: 4 time-slots x 24 j per block (R7) --------
__global__ __launch_bounds__(256) void k_sensory(const float* __restrict__ gx,
        const float* __restrict__ iw, const float* __restrict__ ib,
        const float4* __restrict__ p4,
        float* __restrict__ wnum, float* __restrict__ wden) {
  __shared__ float xs[4 * 1283];
  const int t = threadIdx.x, bid = blockIdx.x;
  const int bs0 = (bid >> 1) * 4;
  const int jbase = (bid & 1) * 24;
  for (int idx = t; idx < 4 * 1283; idx += 256) {
    int slot = idx / 1283, i = idx - slot * 1283;
    xs[idx] = gx[(bs0 + slot) * 1283 + i] * iw[i] + ib[i];
  }
  __syncthreads();
  const int w = t >> 6, l = t & 63;
  for (int jj = 0; jj < 6; ++jj) {
    int j = jbase + w * 6 + jj;
    const float4* pp = p4 + j * 1283;
    float an[4], ad[4];
#pragma unroll
    for (int s2 = 0; s2 < 4; ++s2) { an[s2] = 0.f; ad[s2] = 0.f; }
    for (int i = l; i < 1283; i += 64) {
      float4 P = pp[i];
#pragma unroll
      for (int s2 = 0; s2 < 4; ++s2) {
        float sg = sigmoid_f((xs[s2 * 1283 + i] - P.y) * P.x);
        an[s2] += P.w * sg;
        ad[s2] += P.z * sg;
      }
    }
#pragma unroll
    for (int off = 32; off; off >>= 1)
#pragma unroll
      for (int s2 = 0; s2 < 4; ++s2) {
        an[s2] += __shfl_xor(an[s2], off);
        ad[s2] += __shfl_xor(ad[s2], off);
      }
    if (l == 0) {
#pragma unroll
      for (int s2 = 0; s2 < 4; ++s2) {
        wnum[(bs0 + s2) * 48 + j] = an[s2];
        wden[(bs0 + s2) * 48 + j] = ad[s2];
      }
    }
  }
}

// -------- LTC scan: ONE WAVE per batch, v in registers, zero barriers -----
// lane = (j16, q): posts {j16+16p, p<3}, pres [12q, 12q+12). Butterfly
// shfl_xor(16/32) gives ALL lanes the full sums -> every lane redundantly
// updates all 3 posts (bit-identical across q). Pre-v gather: lane l
// submits v[l>>4] (= v of post l), pullers __shfl from lane i. P[3][12]
// float4 = 144 VGPR — fine at 1 wave/block (32 blocks on 256 CUs).
__global__ __launch_bounds__(64) void k_scan(const float4* __restrict__ r4,
        const float* __restrict__ wnum, const float* __restrict__ wden,
        const float* __restrict__ gleak, const float* __restrict__ vleak,
        const float* __restrict__ cm,
        const float* __restrict__ w_out, const float* __restrict__ b_out,
        const float* __restrict__ w_head, const float* __restrict__ b_head,
        float* __restrict__ out) {
  __shared__ float swn[2304], swd[2304];
  const int t = threadIdx.x, b = blockIdx.x;
  const int j16 = t & 15, q = t >> 4;

  const float* gn = wnum + b * 2304;
  const float* gd = wden + b * 2304;
  for (int k = t; k < 2304; k += 64) { swn[k] = gn[k]; swd[k] = gd[k]; }

  float4 P[3][12];
  float cmt[3], gl[3], glv[3];
#pragma unroll
  for (int p = 0; p < 3; ++p) {
    int j = j16 + 16 * p;
#pragma unroll
    for (int k = 0; k < 12; ++k) P[p][k] = r4[(12 * q + k) * 48 + j];
    cmt[p] = cm[j] * 6.f;
    gl[p] = gleak[j];
    glv[p] = gl[p] * vleak[j];
  }
  float v0 = 0.f, v1 = 0.f, v2 = 0.f;
  float psum = 0.f;
  __syncthreads();

  for (int s = 0; s < 48; ++s) {
    float wns[3], wds[3];
#pragma unroll
    for (int p = 0; p < 3; ++p) {
      wns[p] = swn[s * 48 + j16 + 16 * p];
      wds[p] = swd[s * 48 + j16 + 16 * p];
    }
#pragma unroll 1
    for (int u = 0; u < 6; ++u) {
      float vsub = (q == 0) ? v0 : ((q == 1) ? v1 : v2);
      float vv[12];
#pragma unroll
      for (int k = 0; k < 12; ++k) vv[k] = __shfl(vsub, 12 * q + k);
      float an[3] = {0.f, 0.f, 0.f}, ad[3] = {0.f, 0.f, 0.f};
#pragma unroll
      for (int p = 0; p < 3; ++p)
#pragma unroll
        for (int k = 0; k < 12; ++k) {
          float4 Pp = P[p][k];
          float e = __expf((Pp.x - vv[k]) * Pp.y);   // exp(-z)
          float sg = __builtin_amdgcn_rcpf(1.f + e);
          an[p] += Pp.w * sg;
          ad[p] += Pp.z * sg;
        }
#pragma unroll
      for (int p = 0; p < 3; ++p) {
        an[p] += __shfl_xor(an[p], 16); ad[p] += __shfl_xor(ad[p], 16);
        an[p] += __shfl_xor(an[p], 32); ad[p] += __shfl_xor(ad[p], 32);
      }
      float vn[3];
#pragma unroll
      for (int p = 0; p < 3; ++p) {
        float num = cmt[p] * ((p == 0) ? v0 : (p == 1) ? v1 : v2) + glv[p] + an[p] + wns[p];
        float den = cmt[p] + gl[p] + ad[p] + wds[p] + 1e-8f;
        float r = __builtin_amdgcn_rcpf(den);
        r = r * (2.f - den * r);                  // 1 Newton step
        vn[p] = num * r;
      }
      v0 = vn[0]; v1 = vn[1]; v2 = vn[2];
    }
    psum += v0;    // post j16 (p=0); used by lanes j16<4
  }
  float m = psum * (1.f / 48.f);
  float m0 = __shfl(m, 0), m1 = __shfl(m, 1), m2 = __shfl(m, 2), m3 = __shfl(m, 3);
  if (t < 2) {
    float a = b_head[t];
    a += (m0 * w_out[0] + b_out[0]) * w_head[0 * 2 + t];
    a += (m1 * w_out[1] + b_out[1]) * w_head[1 * 2 + t];
    a += (m2 * w_out[2] + b_out[2]) * w_head[2 * 2 + t];
    a += (m3 * w_out[3] + b_out[3]) * w_head[3 * 2 + t];
    out[b * 2 + t] = tanhf(a);
  }
}

extern "C" void kernel_launch(void* const* d_in, const int* in_sizes, int n_in,
                              void* d_out, int out_size, void* d_ws, size_t ws_size,
                              hipStream_t stream) {
  const float* image   = (const float*)d_in[0];
  const float* rel     = (const float*)d_in[1];
  const float* w0      = (const float*)d_in[2];
  const float* b0      = (const float*)d_in[3];
  const float* w1      = (const float*)d_in[4];
  const float* b1      = (const float*)d_in[5];
  const float* w2      = (const float*)d_in[6];
  const float* b2      = (const float*)d_in[7];
  const float* iw      = (const float*)d_in[8];
  const float* ib      = (const float*)d_in[9];
  const float* gleak   = (const float*)d_in[10];
  const float* vleak   = (const float*)d_in[11];
  const float* cm      = (const float*)d_in[12];
  const float* sigma   = (const float*)d_in[13];
  const float* mu      = (const float*)d_in[14];
  const float* w_syn   = (const float*)d_in[15];
  const float* erev    = (const float*)d_in[16];
  const float* s_sigma = (const float*)d_in[17];
  const float* s_mu    = (const float*)d_in[18];
  const float* s_w     = (const float*)d_in[19];
  const float* s_erev  = (const float*)d_in[20];
  const float* w_out   = (const float*)d_in[21];
  const float* b_out   = (const float*)d_in[22];
  const float* w_head  = (const float*)d_in[23];
  const float* b_head  = (const float*)d_in[24];
  const int* syn_mask  = (const int*)d_in[25];
  const int* sens_mask = (const int*)d_in[26];
  float* ws  = (float*)d_ws;
  float* out = (float*)d_out;

  hipFuncSetAttribute((const void*)k_cnn,
                      hipFuncAttributeMaxDynamicSharedMemorySize, 131072);

  k_pre<<<394, 256, 0, stream>>>(s_sigma, s_mu, s_w, s_erev, sens_mask,
      w_syn, erev, syn_mask, mu, sigma, w1, w2,
      (float4*)(ws + O_SP4), (float4*)(ws + O_R4),
      (ushortx*)(ws + O_W1H), (ushortx*)(ws + O_W1L),
      (ushortx*)(ws + O_W3H), (ushortx*)(ws + O_W3L));

  k_cnn<<<1536, 512, 121088, stream>>>(image, w0, b0,
      (const ushortx*)(ws + O_W1H), (const ushortx*)(ws + O_W1L), b1,
      (const ushortx*)(ws + O_W3H), (const ushortx*)(ws + O_W3L), b2,
      rel, ws + O_X);

  k_sensory<<<768, 256, 0, stream>>>(ws + O_X, iw, ib,
      (const float4*)(ws + O_SP4), ws + O_WNUM, ws + O_WDEN);

  k_scan<<<32, 64, 0, stream>>>((const float4*)(ws + O_R4),
      ws + O_WNUM, ws + O_WDEN, gleak, vleak, cm,
      w_out, b_out, w_head, b_head, out);
}